// Round 2
// baseline (2666.519 us; speedup 1.0000x reference)
//
#include <hip/hip_runtime.h>
#include <math.h>

#define Bsz 256
#define Tsz 128
#define Esz 256
#define Hsz 256
#define Gsz 1024   // 4*H
#define Osz 1024
#define KFC 32768  // T*H
#define KSPLIT 32

__device__ __forceinline__ float sigmoidf_(float x) { return 1.0f / (1.0f + expf(-x)); }

// out[k*N + n] = in[n*K + k]   (transpose [N,K] -> [K,N])
__global__ void transpose_kn(const float* __restrict__ in, float* __restrict__ out, int N, int K) {
    int i = blockIdx.x * blockDim.x + threadIdx.x;
    if (i >= N * K) return;
    int k = i / N;
    int n = i - k * N;
    out[i] = in[n * K + k];
}

// ---------------------------------------------------------------------------
// 128x128-tile fp32 GEMM: C = A[M,K]*W[N,K]^T. 256 thr, 8x8 acc, k-chunk 16,
// register prefetch of next chunk. BIAS=1: +bias, direct store (no K-split).
// BIAS=0: blockIdx.z selects K-slice of length klen, stores to partial slice.
// ---------------------------------------------------------------------------
template <int BIAS>
__global__ __launch_bounds__(256, 2) void gemm128(const float* __restrict__ A, int lda,
                                                  const float* __restrict__ W, int ldw,
                                                  const float* __restrict__ bih,
                                                  const float* __restrict__ bhh,
                                                  float* __restrict__ C, int ldc,
                                                  int klen) {
    __shared__ float As[16][132];
    __shared__ float Bs[16][132];
    int tid = threadIdx.x;
    int tm = tid & 15, tn = tid >> 4;          // 16x16 thread grid, 8x8 outputs each
    int lrow = tid >> 1, lkc = (tid & 1) * 8;  // staging: row 0..127, k-offset 0 or 8
    int kbase = blockIdx.z * klen;
    const float* Ap = A + (size_t)(blockIdx.x * 128 + lrow) * lda + kbase + lkc;
    const float* Wp = W + (size_t)(blockIdx.y * 128 + lrow) * ldw + kbase + lkc;
    float4 pa0, pa1, pb0, pb1;
    pa0 = *(const float4*)(Ap);     pa1 = *(const float4*)(Ap + 4);
    pb0 = *(const float4*)(Wp);     pb1 = *(const float4*)(Wp + 4);
    float acc[8][8] = {};
    int nc = klen >> 4;
    for (int c = 0; c < nc; ++c) {
        __syncthreads();
        As[lkc + 0][lrow] = pa0.x; As[lkc + 1][lrow] = pa0.y; As[lkc + 2][lrow] = pa0.z; As[lkc + 3][lrow] = pa0.w;
        As[lkc + 4][lrow] = pa1.x; As[lkc + 5][lrow] = pa1.y; As[lkc + 6][lrow] = pa1.z; As[lkc + 7][lrow] = pa1.w;
        Bs[lkc + 0][lrow] = pb0.x; Bs[lkc + 1][lrow] = pb0.y; Bs[lkc + 2][lrow] = pb0.z; Bs[lkc + 3][lrow] = pb0.w;
        Bs[lkc + 4][lrow] = pb1.x; Bs[lkc + 5][lrow] = pb1.y; Bs[lkc + 6][lrow] = pb1.z; Bs[lkc + 7][lrow] = pb1.w;
        __syncthreads();
        if (c + 1 < nc) {
            int off = (c + 1) * 16;
            pa0 = *(const float4*)(Ap + off);     pa1 = *(const float4*)(Ap + off + 4);
            pb0 = *(const float4*)(Wp + off);     pb1 = *(const float4*)(Wp + off + 4);
        }
#pragma unroll
        for (int kk = 0; kk < 16; ++kk) {
            float4 a0 = *(const float4*)&As[kk][tm * 8];
            float4 a1 = *(const float4*)&As[kk][tm * 8 + 4];
            float4 b0 = *(const float4*)&Bs[kk][tn * 8];
            float4 b1 = *(const float4*)&Bs[kk][tn * 8 + 4];
            float ar[8] = {a0.x, a0.y, a0.z, a0.w, a1.x, a1.y, a1.z, a1.w};
            float br[8] = {b0.x, b0.y, b0.z, b0.w, b1.x, b1.y, b1.z, b1.w};
#pragma unroll
            for (int i = 0; i < 8; ++i)
#pragma unroll
                for (int j = 0; j < 8; ++j) acc[i][j] += ar[i] * br[j];
        }
    }
    int row0 = blockIdx.x * 128 + tm * 8;
    int col0 = blockIdx.y * 128 + tn * 8;
    float* Cout = C + (BIAS ? 0 : (size_t)blockIdx.z * Bsz * Osz);
    float bias[8];
#pragma unroll
    for (int j = 0; j < 8; ++j) bias[j] = BIAS ? (bih[col0 + j] + bhh[col0 + j]) : 0.f;
#pragma unroll
    for (int i = 0; i < 8; ++i) {
        float4 o0, o1;
        o0.x = acc[i][0] + bias[0]; o0.y = acc[i][1] + bias[1];
        o0.z = acc[i][2] + bias[2]; o0.w = acc[i][3] + bias[3];
        o1.x = acc[i][4] + bias[4]; o1.y = acc[i][5] + bias[5];
        o1.z = acc[i][6] + bias[6]; o1.w = acc[i][7] + bias[7];
        *(float4*)&Cout[(size_t)(row0 + i) * ldc + col0] = o0;
        *(float4*)&Cout[(size_t)(row0 + i) * ldc + col0 + 4] = o1;
    }
}

// out[m][n] = b_fc[n] + sum_ks P[ks][m][n]
__global__ void reduce_out(const float* __restrict__ P, const float* __restrict__ bfc,
                           float* __restrict__ out) {
    int i = blockIdx.x * blockDim.x + threadIdx.x;
    if (i >= Bsz * Osz) return;
    float s = bfc[i & (Osz - 1)];
#pragma unroll
    for (int ks = 0; ks < KSPLIT; ++ks) s += P[(size_t)ks * Bsz * Osz + i];
    out[i] = s;
}

// accumulate a0[r] += sum_k WT[k][col0]*HV[k].r ; a1 likewise for col1
__device__ __forceinline__ void matvec_acc(const float* __restrict__ WT, const float4* HV, int len,
                                           int col0, int col1, float a0[4], float a1[4]) {
    float wa0[4], wa1[4], wb0[4], wb1[4];
#pragma unroll
    for (int q = 0; q < 4; ++q) { wa0[q] = WT[q * Gsz + col0]; wa1[q] = WT[q * Gsz + col1]; }
    for (int k = 0; k < len; k += 8) {
#pragma unroll
        for (int q = 0; q < 4; ++q) {
            int kk = (k + 4 + q) & (len - 1);
            wb0[q] = WT[kk * Gsz + col0]; wb1[q] = WT[kk * Gsz + col1];
        }
#pragma unroll
        for (int q = 0; q < 4; ++q) {
            float4 hq = HV[k + q];
            a0[0] += wa0[q] * hq.x; a0[1] += wa0[q] * hq.y; a0[2] += wa0[q] * hq.z; a0[3] += wa0[q] * hq.w;
            a1[0] += wa1[q] * hq.x; a1[1] += wa1[q] * hq.y; a1[2] += wa1[q] * hq.z; a1[3] += wa1[q] * hq.w;
        }
#pragma unroll
        for (int q = 0; q < 4; ++q) {
            int kk = (k + 8 + q) & (len - 1);
            wa0[q] = WT[kk * Gsz + col0]; wa1[q] = WT[kk * Gsz + col1];
        }
#pragma unroll
        for (int q = 0; q < 4; ++q) {
            float4 hq = HV[k + 4 + q];
            a0[0] += wb0[q] * hq.x; a0[1] += wb0[q] * hq.y; a0[2] += wb0[q] * hq.z; a0[3] += wb0[q] * hq.w;
            a1[0] += wb1[q] * hq.x; a1[1] += wb1[q] * hq.y; a1[2] += wb1[q] * hq.z; a1[3] += wb1[q] * hq.w;
        }
    }
}

// One workgroup = 4 batch rows, 512 threads. Thread j owns gate cols j and j+512.
// XGF=0: xgin = precomputed x_gates [B,T,4H]. XGF=1: xgin = x [B,T,E], gates on the fly.
template <int XGF>
__global__ __launch_bounds__(512) void lstm_scan(const float* __restrict__ xgin,
                                                 const float* __restrict__ whhT,
                                                 const float* __restrict__ wihT,
                                                 const float* __restrict__ bih,
                                                 const float* __restrict__ bhh,
                                                 float* __restrict__ hs) {
    int j = threadIdx.x;            // 0..511
    int b0 = blockIdx.x * 4;
    int col0 = j, col1 = j + 512;   // j<256: (i,g); j>=256: (f,o)
    __shared__ float4 h4[Hsz];      // h4[k] = h for batch rows b0..b0+3
    __shared__ float4 x4[Esz];      // only used when XGF=1
    __shared__ float fo[2][4][Hsz]; // sigmoid(f), sigmoid(o)
    float c[4] = {0.f, 0.f, 0.f, 0.f};
    float bias0 = 0.f, bias1 = 0.f;
    if (XGF) { bias0 = bih[col0] + bhh[col0]; bias1 = bih[col1] + bhh[col1]; }
    if (j < Hsz) h4[j] = make_float4(0.f, 0.f, 0.f, 0.f);
    __syncthreads();

    for (int t = 0; t < Tsz; ++t) {
        float a0[4], a1[4];
        if (XGF) {
#pragma unroll
            for (int r = 0; r < 4; ++r) { a0[r] = bias0; a1[r] = bias1; }
            if (j < Esz) {
                float4 v;
                v.x = xgin[((size_t)(b0 + 0) * Tsz + t) * Esz + j];
                v.y = xgin[((size_t)(b0 + 1) * Tsz + t) * Esz + j];
                v.z = xgin[((size_t)(b0 + 2) * Tsz + t) * Esz + j];
                v.w = xgin[((size_t)(b0 + 3) * Tsz + t) * Esz + j];
                x4[j] = v;
            }
            __syncthreads();
            matvec_acc(wihT, x4, Esz, col0, col1, a0, a1);
        } else {
#pragma unroll
            for (int r = 0; r < 4; ++r) {
                a0[r] = xgin[((size_t)(b0 + r) * Tsz + t) * Gsz + col0];
                a1[r] = xgin[((size_t)(b0 + r) * Tsz + t) * Gsz + col1];
            }
        }
        matvec_acc(whhT, h4, Hsz, col0, col1, a0, a1);

        if (j < Hsz) {
#pragma unroll
            for (int r = 0; r < 4; ++r) { a0[r] = sigmoidf_(a0[r]); a1[r] = tanhf(a1[r]); } // i, g
        } else {
#pragma unroll
            for (int r = 0; r < 4; ++r) {
                fo[0][r][j - Hsz] = sigmoidf_(a0[r]); // f
                fo[1][r][j - Hsz] = sigmoidf_(a1[r]); // o
            }
        }
        __syncthreads();
        if (j < Hsz) {
            float hv[4];
#pragma unroll
            for (int r = 0; r < 4; ++r) {
                float f = fo[0][r][j], o = fo[1][r][j];
                c[r] = f * c[r] + a0[r] * a1[r];
                hv[r] = o * tanhf(c[r]);
                hs[(size_t)(b0 + r) * KFC + t * Hsz + j] = hv[r];
            }
            h4[j] = make_float4(hv[0], hv[1], hv[2], hv[3]);
        }
        __syncthreads();
    }
}

extern "C" void kernel_launch(void* const* d_in, const int* in_sizes, int n_in,
                              void* d_out, int out_size, void* d_ws, size_t ws_size,
                              hipStream_t stream) {
    const float* x    = (const float*)d_in[0];
    const float* w_ih = (const float*)d_in[1];
    const float* w_hh = (const float*)d_in[2];
    const float* b_ih = (const float*)d_in[3];
    const float* b_hh = (const float*)d_in[4];
    const float* w_fc = (const float*)d_in[5];
    const float* b_fc = (const float*)d_in[6];
    float* out = (float*)d_out;
    char* ws = (char*)d_ws;

    const size_t XG_BYTES = (size_t)Bsz * Tsz * Gsz * 4;    // 128 MB
    const size_t WT_BYTES = (size_t)Esz * Gsz * 4;          // 1 MB
    const size_t HS_BYTES = (size_t)Bsz * KFC * 4;          // 32 MB
    const size_t P_BYTES  = (size_t)KSPLIT * Bsz * Osz * 4; // 32 MB
    bool fast = ws_size >= XG_BYTES + WT_BYTES + HS_BYTES + P_BYTES;

    const int KLEN = KFC / KSPLIT;  // 1024

    if (fast) {
        float* xg   = (float*)(ws);
        float* whhT = (float*)(ws + XG_BYTES);
        float* hsb  = (float*)(ws + XG_BYTES + WT_BYTES);
        float* part = (float*)(ws + XG_BYTES + WT_BYTES + HS_BYTES);
        transpose_kn<<<(Esz * Gsz + 255) / 256, 256, 0, stream>>>(w_hh, whhT, Gsz, Esz);
        gemm128<1><<<dim3(Bsz * Tsz / 128, Gsz / 128, 1), 256, 0, stream>>>(
            x, Esz, w_ih, Esz, b_ih, b_hh, xg, Gsz, Esz);
        lstm_scan<0><<<Bsz / 4, 512, 0, stream>>>(xg, whhT, nullptr, b_ih, b_hh, hsb);
        gemm128<0><<<dim3(Bsz / 128, Osz / 128, KSPLIT), 256, 0, stream>>>(
            hsb, KFC, w_fc, KFC, nullptr, nullptr, part, Osz, KLEN);
        reduce_out<<<(Bsz * Osz + 255) / 256, 256, 0, stream>>>(part, b_fc, out);
    } else {
        float* whhT = (float*)(ws);
        float* wihT = (float*)(ws + WT_BYTES);
        float* hsb  = (float*)(ws + 2 * WT_BYTES);
        float* part = (float*)(ws + 2 * WT_BYTES + HS_BYTES);
        transpose_kn<<<(Esz * Gsz + 255) / 256, 256, 0, stream>>>(w_hh, whhT, Gsz, Esz);
        transpose_kn<<<(Esz * Gsz + 255) / 256, 256, 0, stream>>>(w_ih, wihT, Gsz, Esz);
        lstm_scan<1><<<Bsz / 4, 512, 0, stream>>>(x, whhT, wihT, b_ih, b_hh, hsb);
        gemm128<0><<<dim3(Bsz / 128, Osz / 128, KSPLIT), 256, 0, stream>>>(
            hsb, KFC, w_fc, KFC, nullptr, nullptr, part, Osz, KLEN);
        reduce_out<<<(Bsz * Osz + 255) / 256, 256, 0, stream>>>(part, b_fc, out);
    }
}

// Round 3
// 2250.730 us; speedup vs baseline: 1.1847x; 1.1847x over previous
//
#include <hip/hip_runtime.h>
#include <math.h>

#define Bsz 256
#define Tsz 128
#define Esz 256
#define Hsz 256
#define Gsz 1024   // 4*H
#define Osz 1024
#define KFC 32768  // T*H
#define KSPLIT 32
#define NBI 16     // batch groups (16 rows each)
#define NHJ 16     // h-col groups (16 cols each)

__device__ __forceinline__ float sigmoidf_(float x) { return 1.0f / (1.0f + expf(-x)); }

// out[k*N + n] = in[n*K + k]   (transpose [N,K] -> [K,N])
__global__ void transpose_kn(const float* __restrict__ in, float* __restrict__ out, int N, int K) {
    int i = blockIdx.x * blockDim.x + threadIdx.x;
    if (i >= N * K) return;
    int k = i / N;
    int n = i - k * N;
    out[i] = in[n * K + k];
}

// ---------------------------------------------------------------------------
// 128x128-tile fp32 GEMM: C = A[M,K]*W[N,K]^T. 256 thr, 8x8 acc, k-chunk 16,
// register prefetch. BIAS=1: +bias, direct store. BIAS=0: blockIdx.z K-slice.
// ---------------------------------------------------------------------------
template <int BIAS>
__global__ __launch_bounds__(256, 2) void gemm128(const float* __restrict__ A, int lda,
                                                  const float* __restrict__ W, int ldw,
                                                  const float* __restrict__ bih,
                                                  const float* __restrict__ bhh,
                                                  float* __restrict__ C, int ldc,
                                                  int klen) {
    __shared__ float As[16][132];
    __shared__ float Bs[16][132];
    int tid = threadIdx.x;
    int tm = tid & 15, tn = tid >> 4;
    int lrow = tid >> 1, lkc = (tid & 1) * 8;
    int kbase = blockIdx.z * klen;
    const float* Ap = A + (size_t)(blockIdx.x * 128 + lrow) * lda + kbase + lkc;
    const float* Wp = W + (size_t)(blockIdx.y * 128 + lrow) * ldw + kbase + lkc;
    float4 pa0, pa1, pb0, pb1;
    pa0 = *(const float4*)(Ap);     pa1 = *(const float4*)(Ap + 4);
    pb0 = *(const float4*)(Wp);     pb1 = *(const float4*)(Wp + 4);
    float acc[8][8] = {};
    int nc = klen >> 4;
    for (int c = 0; c < nc; ++c) {
        __syncthreads();
        As[lkc + 0][lrow] = pa0.x; As[lkc + 1][lrow] = pa0.y; As[lkc + 2][lrow] = pa0.z; As[lkc + 3][lrow] = pa0.w;
        As[lkc + 4][lrow] = pa1.x; As[lkc + 5][lrow] = pa1.y; As[lkc + 6][lrow] = pa1.z; As[lkc + 7][lrow] = pa1.w;
        Bs[lkc + 0][lrow] = pb0.x; Bs[lkc + 1][lrow] = pb0.y; Bs[lkc + 2][lrow] = pb0.z; Bs[lkc + 3][lrow] = pb0.w;
        Bs[lkc + 4][lrow] = pb1.x; Bs[lkc + 5][lrow] = pb1.y; Bs[lkc + 6][lrow] = pb1.z; Bs[lkc + 7][lrow] = pb1.w;
        __syncthreads();
        if (c + 1 < nc) {
            int off = (c + 1) * 16;
            pa0 = *(const float4*)(Ap + off);     pa1 = *(const float4*)(Ap + off + 4);
            pb0 = *(const float4*)(Wp + off);     pb1 = *(const float4*)(Wp + off + 4);
        }
#pragma unroll
        for (int kk = 0; kk < 16; ++kk) {
            float4 a0 = *(const float4*)&As[kk][tm * 8];
            float4 a1 = *(const float4*)&As[kk][tm * 8 + 4];
            float4 b0 = *(const float4*)&Bs[kk][tn * 8];
            float4 b1 = *(const float4*)&Bs[kk][tn * 8 + 4];
            float ar[8] = {a0.x, a0.y, a0.z, a0.w, a1.x, a1.y, a1.z, a1.w};
            float br[8] = {b0.x, b0.y, b0.z, b0.w, b1.x, b1.y, b1.z, b1.w};
#pragma unroll
            for (int i = 0; i < 8; ++i)
#pragma unroll
                for (int j = 0; j < 8; ++j) acc[i][j] += ar[i] * br[j];
        }
    }
    int row0 = blockIdx.x * 128 + tm * 8;
    int col0 = blockIdx.y * 128 + tn * 8;
    float* Cout = C + (BIAS ? 0 : (size_t)blockIdx.z * Bsz * Osz);
    float bias[8];
#pragma unroll
    for (int j = 0; j < 8; ++j) bias[j] = BIAS ? (bih[col0 + j] + bhh[col0 + j]) : 0.f;
#pragma unroll
    for (int i = 0; i < 8; ++i) {
        float4 o0, o1;
        o0.x = acc[i][0] + bias[0]; o0.y = acc[i][1] + bias[1];
        o0.z = acc[i][2] + bias[2]; o0.w = acc[i][3] + bias[3];
        o1.x = acc[i][4] + bias[4]; o1.y = acc[i][5] + bias[5];
        o1.z = acc[i][6] + bias[6]; o1.w = acc[i][7] + bias[7];
        *(float4*)&Cout[(size_t)(row0 + i) * ldc + col0] = o0;
        *(float4*)&Cout[(size_t)(row0 + i) * ldc + col0 + 4] = o1;
    }
}

// out[m][n] = b_fc[n] + sum_ks P[ks][m][n]
__global__ void reduce_out(const float* __restrict__ P, const float* __restrict__ bfc,
                           float* __restrict__ out) {
    int i = blockIdx.x * blockDim.x + threadIdx.x;
    if (i >= Bsz * Osz) return;
    float s = bfc[i & (Osz - 1)];
#pragma unroll
    for (int ks = 0; ks < KSPLIT; ++ks) s += P[(size_t)ks * Bsz * Osz + i];
    out[i] = s;
}

// ---------------------------------------------------------------------------
// Cooperative LSTM scan. Grid (NHJ, NBI) = 256 WGs, 256 thr each, 1 WG/CU
// (97 KB LDS forces exclusive residency -> all WGs co-resident, spin is safe).
// WG(bi,hj): batch rows [16bi,16bi+16), h cols [16hj,16hj+16) (=64 gate cols).
// Weights LDS-resident across all 128 steps. h broadcast via global hbuf
// (parity double buffer) + per-bi release/acquire atomic counter.
// ---------------------------------------------------------------------------
__global__ __launch_bounds__(256, 1) void lstm_scan_coop(
    const float* __restrict__ xg,    // [B*T][1024] (bias already added)
    const float* __restrict__ whhT,  // [256][1024]
    float* __restrict__ hs,          // [B][KFC]
    float* __restrict__ hbuf,        // [NBI][2][256][16]  (zeroed)
    unsigned int* __restrict__ cnt)  // [NBI*16] (zeroed)
{
    int hj = blockIdx.x, bi = blockIdx.y;
    int tid = threadIdx.x;
    __shared__ float Wl[256][64];     // 64 KB, Wl[k][g*16+c]
    __shared__ float HT[256][16];     // 16 KB, HT[k][r]
    __shared__ float Pp[4][16][68];   // 17.4 KB partials (padded)

    // one-time weight stage: cols {g*256 + hj*16 + c}
    for (int idx = tid; idx < 256 * 64; idx += 256) {
        int k = idx >> 6, lc = idx & 63;
        int g = lc >> 4, cc = lc & 15;
        Wl[k][lc] = whhT[(size_t)k * Gsz + g * 256 + hj * 16 + cc];
    }
    int ks = tid >> 6;            // k-slice (wave) 0..3
    int rgrp = (tid >> 4) & 3;    // 0..3 (4 rows)
    int cgrp = tid & 15;          // 0..15 (4 cols)
    int r_a = tid >> 4;           // activation row 0..15
    int hc_a = tid & 15;          // activation h-col 0..15
    float c_state = 0.f;
    float* hb = hbuf + (size_t)bi * 2 * 4096;
    unsigned int* myc = cnt + bi * 16;  // 64B-padded slot
    __syncthreads();

    for (int t = 0; t < Tsz; ++t) {
        int p = t & 1;
        // stage H^T[256][16] from hbuf (coalesced float4)
        {
            const float4* src = (const float4*)(hb + (size_t)p * 4096);
            float4* dst = (float4*)HT;
#pragma unroll
            for (int i = 0; i < 4; ++i) dst[tid + 256 * i] = src[tid + 256 * i];
        }
        __syncthreads();
        // GEMM: acc[4r][4c] over this wave's 64-k slice
        float acc[4][4] = {};
#pragma unroll 8
        for (int kk = 0; kk < 64; ++kk) {
            int k = ks * 64 + kk;
            float4 hv = *(const float4*)&HT[k][rgrp * 4];
            float4 wv = *(const float4*)&Wl[k][cgrp * 4];
            float hr[4] = {hv.x, hv.y, hv.z, hv.w};
            float wr[4] = {wv.x, wv.y, wv.z, wv.w};
#pragma unroll
            for (int i = 0; i < 4; ++i)
#pragma unroll
                for (int j = 0; j < 4; ++j) acc[i][j] += hr[i] * wr[j];
        }
#pragma unroll
        for (int i = 0; i < 4; ++i)
            *(float4*)&Pp[ks][rgrp * 4 + i][cgrp * 4] =
                make_float4(acc[i][0], acc[i][1], acc[i][2], acc[i][3]);
        __syncthreads();
        // reduce + activations: thread (r_a, hc_a)
        float gi = 0.f, gf = 0.f, gg = 0.f, go = 0.f;
#pragma unroll
        for (int s = 0; s < 4; ++s) {
            gi += Pp[s][r_a][0 * 16 + hc_a];
            gf += Pp[s][r_a][1 * 16 + hc_a];
            gg += Pp[s][r_a][2 * 16 + hc_a];
            go += Pp[s][r_a][3 * 16 + hc_a];
        }
        size_t xo = ((size_t)(bi * 16 + r_a) * Tsz + t) * Gsz + hj * 16 + hc_a;
        gi += xg[xo];
        gf += xg[xo + 256];
        gg += xg[xo + 512];
        go += xg[xo + 768];
        gi = sigmoidf_(gi); gf = sigmoidf_(gf); gg = tanhf(gg); go = sigmoidf_(go);
        c_state = gf * c_state + gi * gg;
        float hval = go * tanhf(c_state);
        hs[(size_t)(bi * 16 + r_a) * KFC + t * Hsz + hj * 16 + hc_a] = hval;
        hb[(size_t)(p ^ 1) * 4096 + (hj * 16 + hc_a) * 16 + r_a] = hval;
        __syncthreads();  // drains vmcnt: all stores reached L2 before release
        if (t < Tsz - 1) {
            if (tid == 0) {
                __hip_atomic_fetch_add(myc, 1u, __ATOMIC_RELEASE, __HIP_MEMORY_SCOPE_AGENT);
                unsigned target = 16u * (unsigned)(t + 1);
                long guard = 0;
                while (__hip_atomic_load(myc, __ATOMIC_ACQUIRE, __HIP_MEMORY_SCOPE_AGENT) < target) {
                    if (++guard > (1L << 24)) break;  // safety bound, never hit if resident
                }
            }
            __syncthreads();
        }
    }
}

// old per-WG scan kept only as small-ws fallback
__device__ __forceinline__ void matvec_acc(const float* __restrict__ WT, const float4* HV, int len,
                                           int col0, int col1, float a0[4], float a1[4]) {
    float wa0[4], wa1[4], wb0[4], wb1[4];
#pragma unroll
    for (int q = 0; q < 4; ++q) { wa0[q] = WT[q * Gsz + col0]; wa1[q] = WT[q * Gsz + col1]; }
    for (int k = 0; k < len; k += 8) {
#pragma unroll
        for (int q = 0; q < 4; ++q) {
            int kk = (k + 4 + q) & (len - 1);
            wb0[q] = WT[kk * Gsz + col0]; wb1[q] = WT[kk * Gsz + col1];
        }
#pragma unroll
        for (int q = 0; q < 4; ++q) {
            float4 hq = HV[k + q];
            a0[0] += wa0[q] * hq.x; a0[1] += wa0[q] * hq.y; a0[2] += wa0[q] * hq.z; a0[3] += wa0[q] * hq.w;
            a1[0] += wa1[q] * hq.x; a1[1] += wa1[q] * hq.y; a1[2] += wa1[q] * hq.z; a1[3] += wa1[q] * hq.w;
        }
#pragma unroll
        for (int q = 0; q < 4; ++q) {
            int kk = (k + 8 + q) & (len - 1);
            wa0[q] = WT[kk * Gsz + col0]; wa1[q] = WT[kk * Gsz + col1];
        }
#pragma unroll
        for (int q = 0; q < 4; ++q) {
            float4 hq = HV[k + 4 + q];
            a0[0] += wb0[q] * hq.x; a0[1] += wb0[q] * hq.y; a0[2] += wb0[q] * hq.z; a0[3] += wb0[q] * hq.w;
            a1[0] += wb1[q] * hq.x; a1[1] += wb1[q] * hq.y; a1[2] += wb1[q] * hq.z; a1[3] += wb1[q] * hq.w;
        }
    }
}

template <int XGF>
__global__ __launch_bounds__(512) void lstm_scan(const float* __restrict__ xgin,
                                                 const float* __restrict__ whhT,
                                                 const float* __restrict__ wihT,
                                                 const float* __restrict__ bih,
                                                 const float* __restrict__ bhh,
                                                 float* __restrict__ hs) {
    int j = threadIdx.x;
    int b0 = blockIdx.x * 4;
    int col0 = j, col1 = j + 512;
    __shared__ float4 h4[Hsz];
    __shared__ float4 x4[Esz];
    __shared__ float fo[2][4][Hsz];
    float c[4] = {0.f, 0.f, 0.f, 0.f};
    float bias0 = 0.f, bias1 = 0.f;
    if (XGF) { bias0 = bih[col0] + bhh[col0]; bias1 = bih[col1] + bhh[col1]; }
    if (j < Hsz) h4[j] = make_float4(0.f, 0.f, 0.f, 0.f);
    __syncthreads();
    for (int t = 0; t < Tsz; ++t) {
        float a0[4], a1[4];
        if (XGF) {
#pragma unroll
            for (int r = 0; r < 4; ++r) { a0[r] = bias0; a1[r] = bias1; }
            if (j < Esz) {
                float4 v;
                v.x = xgin[((size_t)(b0 + 0) * Tsz + t) * Esz + j];
                v.y = xgin[((size_t)(b0 + 1) * Tsz + t) * Esz + j];
                v.z = xgin[((size_t)(b0 + 2) * Tsz + t) * Esz + j];
                v.w = xgin[((size_t)(b0 + 3) * Tsz + t) * Esz + j];
                x4[j] = v;
            }
            __syncthreads();
            matvec_acc(wihT, x4, Esz, col0, col1, a0, a1);
        } else {
#pragma unroll
            for (int r = 0; r < 4; ++r) {
                a0[r] = xgin[((size_t)(b0 + r) * Tsz + t) * Gsz + col0];
                a1[r] = xgin[((size_t)(b0 + r) * Tsz + t) * Gsz + col1];
            }
        }
        matvec_acc(whhT, h4, Hsz, col0, col1, a0, a1);
        if (j < Hsz) {
#pragma unroll
            for (int r = 0; r < 4; ++r) { a0[r] = sigmoidf_(a0[r]); a1[r] = tanhf(a1[r]); }
        } else {
#pragma unroll
            for (int r = 0; r < 4; ++r) {
                fo[0][r][j - Hsz] = sigmoidf_(a0[r]);
                fo[1][r][j - Hsz] = sigmoidf_(a1[r]);
            }
        }
        __syncthreads();
        if (j < Hsz) {
            float hv[4];
#pragma unroll
            for (int r = 0; r < 4; ++r) {
                float f = fo[0][r][j], o = fo[1][r][j];
                c[r] = f * c[r] + a0[r] * a1[r];
                hv[r] = o * tanhf(c[r]);
                hs[(size_t)(b0 + r) * KFC + t * Hsz + j] = hv[r];
            }
            h4[j] = make_float4(hv[0], hv[1], hv[2], hv[3]);
        }
        __syncthreads();
    }
}

extern "C" void kernel_launch(void* const* d_in, const int* in_sizes, int n_in,
                              void* d_out, int out_size, void* d_ws, size_t ws_size,
                              hipStream_t stream) {
    const float* x    = (const float*)d_in[0];
    const float* w_ih = (const float*)d_in[1];
    const float* w_hh = (const float*)d_in[2];
    const float* b_ih = (const float*)d_in[3];
    const float* b_hh = (const float*)d_in[4];
    const float* w_fc = (const float*)d_in[5];
    const float* b_fc = (const float*)d_in[6];
    float* out = (float*)d_out;
    char* ws = (char*)d_ws;

    const size_t XG_BYTES = (size_t)Bsz * Tsz * Gsz * 4;    // 128 MB
    const size_t WT_BYTES = (size_t)Esz * Gsz * 4;          // 1 MB
    const size_t HS_BYTES = (size_t)Bsz * KFC * 4;          // 32 MB
    const size_t P_BYTES  = (size_t)KSPLIT * Bsz * Osz * 4; // 32 MB
    const size_t HB_BYTES = (size_t)NBI * 2 * 256 * 16 * 4; // 512 KB
    const size_t CNT_BYTES = (size_t)NBI * 16 * 4;          // 1 KB
    bool fast = ws_size >= XG_BYTES + WT_BYTES + HS_BYTES + P_BYTES + HB_BYTES + CNT_BYTES;

    const int KLEN = KFC / KSPLIT;  // 1024

    if (fast) {
        float* xg   = (float*)(ws);
        float* whhT = (float*)(ws + XG_BYTES);
        float* hsb  = (float*)(ws + XG_BYTES + WT_BYTES);
        float* part = (float*)(ws + XG_BYTES + WT_BYTES + HS_BYTES);
        float* hbuf = (float*)(ws + XG_BYTES + WT_BYTES + HS_BYTES + P_BYTES);
        unsigned int* cnt = (unsigned int*)(ws + XG_BYTES + WT_BYTES + HS_BYTES + P_BYTES + HB_BYTES);
        hipMemsetAsync(hbuf, 0, HB_BYTES + CNT_BYTES, stream);
        transpose_kn<<<(Esz * Gsz + 255) / 256, 256, 0, stream>>>(w_hh, whhT, Gsz, Esz);
        gemm128<1><<<dim3(Bsz * Tsz / 128, Gsz / 128, 1), 256, 0, stream>>>(
            x, Esz, w_ih, Esz, b_ih, b_hh, xg, Gsz, Esz);
        lstm_scan_coop<<<dim3(NHJ, NBI), 256, 0, stream>>>(xg, whhT, hsb, hbuf, cnt);
        gemm128<0><<<dim3(Bsz / 128, Osz / 128, KSPLIT), 256, 0, stream>>>(
            hsb, KFC, w_fc, KFC, nullptr, nullptr, part, Osz, KLEN);
        reduce_out<<<(Bsz * Osz + 255) / 256, 256, 0, stream>>>(part, b_fc, out);
    } else {
        float* whhT = (float*)(ws);
        float* wihT = (float*)(ws + WT_BYTES);
        float* hsb  = (float*)(ws + 2 * WT_BYTES);
        float* part = (float*)(ws + 2 * WT_BYTES + HS_BYTES);
        transpose_kn<<<(Esz * Gsz + 255) / 256, 256, 0, stream>>>(w_hh, whhT, Gsz, Esz);
        transpose_kn<<<(Esz * Gsz + 255) / 256, 256, 0, stream>>>(w_ih, wihT, Gsz, Esz);
        lstm_scan<1><<<Bsz / 4, 512, 0, stream>>>(x, whhT, wihT, b_ih, b_hh, hsb);
        gemm128<0><<<dim3(Bsz / 128, Osz / 128, KSPLIT), 256, 0, stream>>>(
            hsb, KFC, w_fc, KFC, nullptr, nullptr, part, Osz, KLEN);
        reduce_out<<<(Bsz * Osz + 255) / 256, 256, 0, stream>>>(part, b_fc, out);
    }
}

// Round 6
// 1131.614 us; speedup vs baseline: 2.3564x; 1.9890x over previous
//
#include <hip/hip_runtime.h>
#include <math.h>

#define Bsz 256
#define Tsz 128
#define Esz 256
#define Hsz 256
#define Gsz 1024   // 4*H
#define Osz 1024
#define KFC 32768  // T*H
#define KSPLIT 32
#define NBI 16     // batch groups (16 rows each)
#define NHJ 16     // h-col groups (16 cols each)

__device__ __forceinline__ float sigmoidf_(float x) { return 1.0f / (1.0f + expf(-x)); }

// out[k*N + n] = in[n*K + k]   (transpose [N,K] -> [K,N])
__global__ void transpose_kn(const float* __restrict__ in, float* __restrict__ out, int N, int K) {
    int i = blockIdx.x * blockDim.x + threadIdx.x;
    if (i >= N * K) return;
    int k = i / N;
    int n = i - k * N;
    out[i] = in[n * K + k];
}

// ---------------------------------------------------------------------------
// 128x128-tile fp32 GEMM: C = A[M,K]*W[N,K]^T. 256 thr, 8x8 acc, k-chunk 16,
// register prefetch. BIAS=1: +bias, direct store. BIAS=0: blockIdx.z K-slice.
// ---------------------------------------------------------------------------
template <int BIAS>
__global__ __launch_bounds__(256, 2) void gemm128(const float* __restrict__ A, int lda,
                                                  const float* __restrict__ W, int ldw,
                                                  const float* __restrict__ bih,
                                                  const float* __restrict__ bhh,
                                                  float* __restrict__ C, int ldc,
                                                  int klen) {
    __shared__ float As[16][132];
    __shared__ float Bs[16][132];
    int tid = threadIdx.x;
    int tm = tid & 15, tn = tid >> 4;
    int lrow = tid >> 1, lkc = (tid & 1) * 8;
    int kbase = blockIdx.z * klen;
    const float* Ap = A + (size_t)(blockIdx.x * 128 + lrow) * lda + kbase + lkc;
    const float* Wp = W + (size_t)(blockIdx.y * 128 + lrow) * ldw + kbase + lkc;
    float4 pa0, pa1, pb0, pb1;
    pa0 = *(const float4*)(Ap);     pa1 = *(const float4*)(Ap + 4);
    pb0 = *(const float4*)(Wp);     pb1 = *(const float4*)(Wp + 4);
    float acc[8][8] = {};
    int nc = klen >> 4;
    for (int c = 0; c < nc; ++c) {
        __syncthreads();
        As[lkc + 0][lrow] = pa0.x; As[lkc + 1][lrow] = pa0.y; As[lkc + 2][lrow] = pa0.z; As[lkc + 3][lrow] = pa0.w;
        As[lkc + 4][lrow] = pa1.x; As[lkc + 5][lrow] = pa1.y; As[lkc + 6][lrow] = pa1.z; As[lkc + 7][lrow] = pa1.w;
        Bs[lkc + 0][lrow] = pb0.x; Bs[lkc + 1][lrow] = pb0.y; Bs[lkc + 2][lrow] = pb0.z; Bs[lkc + 3][lrow] = pb0.w;
        Bs[lkc + 4][lrow] = pb1.x; Bs[lkc + 5][lrow] = pb1.y; Bs[lkc + 6][lrow] = pb1.z; Bs[lkc + 7][lrow] = pb1.w;
        __syncthreads();
        if (c + 1 < nc) {
            int off = (c + 1) * 16;
            pa0 = *(const float4*)(Ap + off);     pa1 = *(const float4*)(Ap + off + 4);
            pb0 = *(const float4*)(Wp + off);     pb1 = *(const float4*)(Wp + off + 4);
        }
#pragma unroll
        for (int kk = 0; kk < 16; ++kk) {
            float4 a0 = *(const float4*)&As[kk][tm * 8];
            float4 a1 = *(const float4*)&As[kk][tm * 8 + 4];
            float4 b0 = *(const float4*)&Bs[kk][tn * 8];
            float4 b1 = *(const float4*)&Bs[kk][tn * 8 + 4];
            float ar[8] = {a0.x, a0.y, a0.z, a0.w, a1.x, a1.y, a1.z, a1.w};
            float br[8] = {b0.x, b0.y, b0.z, b0.w, b1.x, b1.y, b1.z, b1.w};
#pragma unroll
            for (int i = 0; i < 8; ++i)
#pragma unroll
                for (int j = 0; j < 8; ++j) acc[i][j] += ar[i] * br[j];
        }
    }
    int row0 = blockIdx.x * 128 + tm * 8;
    int col0 = blockIdx.y * 128 + tn * 8;
    float* Cout = C + (BIAS ? 0 : (size_t)blockIdx.z * Bsz * Osz);
    float bias[8];
#pragma unroll
    for (int j = 0; j < 8; ++j) bias[j] = BIAS ? (bih[col0 + j] + bhh[col0 + j]) : 0.f;
#pragma unroll
    for (int i = 0; i < 8; ++i) {
        float4 o0, o1;
        o0.x = acc[i][0] + bias[0]; o0.y = acc[i][1] + bias[1];
        o0.z = acc[i][2] + bias[2]; o0.w = acc[i][3] + bias[3];
        o1.x = acc[i][4] + bias[4]; o1.y = acc[i][5] + bias[5];
        o1.z = acc[i][6] + bias[6]; o1.w = acc[i][7] + bias[7];
        *(float4*)&Cout[(size_t)(row0 + i) * ldc + col0] = o0;
        *(float4*)&Cout[(size_t)(row0 + i) * ldc + col0 + 4] = o1;
    }
}

// out[m][n] = b_fc[n] + sum_ks P[ks][m][n]
__global__ void reduce_out(const float* __restrict__ P, const float* __restrict__ bfc,
                           float* __restrict__ out) {
    int i = blockIdx.x * blockDim.x + threadIdx.x;
    if (i >= Bsz * Osz) return;
    float s = bfc[i & (Osz - 1)];
#pragma unroll
    for (int ks = 0; ks < KSPLIT; ++ks) s += P[(size_t)ks * Bsz * Osz + i];
    out[i] = s;
}

// ---------------------------------------------------------------------------
// Cooperative LSTM scan v2. Grid (NHJ,NBI)=256 WGs x 1024 thr, 1 WG/CU
// (90 KB LDS -> exclusive residency -> all 256 WGs co-resident; spin safe,
// with bounded guard as deadlock escape).
// WG(bi,hj): batch rows [16bi..), h cols [16hj..) (=64 gate cols).
// w_hh slice lives in REGISTERS (16 x float4/thread, all 128 steps).
// Cross-WG h exchange: RELAXED agent atomics only (write-through to IF
// coherence point, L2-bypass reads) -- no buffer_wbl2/buffer_inv cache
// maintenance (round-3 killer). Ordering is structural: h stores drained
// (vmcnt(0) at __syncthreads) BEFORE the counter add; stage loads issued
// only AFTER the counter is observed.
// ---------------------------------------------------------------------------
__global__ __launch_bounds__(1024) void lstm_scan_coop2(
    const float* __restrict__ xg,    // [B*T][1024] (bias pre-added)
    const float* __restrict__ whhT,  // [256][1024]
    float* __restrict__ hs,          // [B][KFC]
    float* hbuf,                     // [NBI][2][4096] zeroed
    unsigned int* cnt)               // [NBI][32] zeroed
{
    const int hj = blockIdx.x, bi = blockIdx.y;
    const int tid = threadIdx.x;
    __shared__ float HT[256][16];     // 16 KB: HT[k][r]
    __shared__ float Pp[16][16][68];  // 69.6 KB partials (padded)
    __shared__ float gbuf[4][16][16]; // 4 KB activated gates

    const int ks   = tid >> 6;        // k-slice (wave) 0..15, 16 k each
    const int rgrp = (tid >> 4) & 3;  // 4-row group
    const int cgrp = tid & 15;        // 16 col-quads
    // one-time: this thread's 16x4 w_hh slice into registers
    const int colbase = (cgrp >> 2) * 256 + hj * 16 + (cgrp & 3) * 4;
    float4 w[16];
#pragma unroll
    for (int kk = 0; kk < 16; ++kk)
        w[kk] = *(const float4*)&whhT[(size_t)(ks * 16 + kk) * Gsz + colbase];

    // reduce-phase mapping: thread = (gate gq, row rq, col hq)
    const int gq = tid >> 8, rq = (tid >> 4) & 15, hq = tid & 15;
    // update-phase mapping (tid<256)
    const int r_a = tid >> 4, hc_a = tid & 15;
    float c_state = 0.f;
    float* hb = hbuf + (size_t)bi * 8192;
    unsigned int* myc = cnt + bi * 32;

    for (int t = 0; t < Tsz; ++t) {
        const int p = t & 1;
        // stage h_{t-1} from IF into LDS (L2-bypass relaxed-agent loads)
        {
            const unsigned int* src = (const unsigned int*)(hb + (size_t)p * 4096);
            float* HTf = &HT[0][0];
#pragma unroll
            for (int i = 0; i < 4; ++i) {
                unsigned int u = __hip_atomic_load(src + tid + 1024 * i,
                                                   __ATOMIC_RELAXED, __HIP_MEMORY_SCOPE_AGENT);
                HTf[tid + 1024 * i] = __uint_as_float(u);
            }
        }
        // prefetch this thread's xg gate value (latency hidden under GEMM)
        float xgv = xg[((size_t)(bi * 16 + rq) * Tsz + t) * Gsz + gq * 256 + hj * 16 + hq];
        __syncthreads();
        // GEMM: acc[4r][4c] over this wave's 16-k slice, w from registers
        float acc[4][4] = {};
#pragma unroll
        for (int kk = 0; kk < 16; ++kk) {
            float4 hv = *(const float4*)&HT[ks * 16 + kk][rgrp * 4];
            float hr[4] = {hv.x, hv.y, hv.z, hv.w};
            float wr[4] = {w[kk].x, w[kk].y, w[kk].z, w[kk].w};
#pragma unroll
            for (int i = 0; i < 4; ++i)
#pragma unroll
                for (int j = 0; j < 4; ++j) acc[i][j] += hr[i] * wr[j];
        }
#pragma unroll
        for (int i = 0; i < 4; ++i)
            *(float4*)&Pp[ks][rgrp * 4 + i][cgrp * 4] =
                make_float4(acc[i][0], acc[i][1], acc[i][2], acc[i][3]);
        __syncthreads();
        // parallel reduce + activation: each thread owns ONE gate value
        {
            float s = 0.f;
#pragma unroll
            for (int sl = 0; sl < 16; ++sl) s += Pp[sl][rq][gq * 16 + hq];
            s += xgv;
            s = (gq == 2) ? tanhf(s) : sigmoidf_(s);   // gq wave-uniform
            gbuf[gq][rq][hq] = s;
        }
        __syncthreads();
        // state update (tid<256)
        if (tid < 256) {
            float gi = gbuf[0][r_a][hc_a];
            float gf = gbuf[1][r_a][hc_a];
            float gg = gbuf[2][r_a][hc_a];
            float go = gbuf[3][r_a][hc_a];
            c_state = gf * c_state + gi * gg;
            float hval = go * tanhf(c_state);
            hs[(size_t)(bi * 16 + r_a) * KFC + t * Hsz + hj * 16 + hc_a] = hval;
            // write-through store to IF (visible to agent readers, no cache maint)
            __hip_atomic_store((unsigned int*)hb + (size_t)(p ^ 1) * 4096 + (hj * 16 + hc_a) * 16 + r_a,
                               __float_as_uint(hval),
                               __ATOMIC_RELAXED, __HIP_MEMORY_SCOPE_AGENT);
        }
        __syncthreads();  // drains vmcnt: all h stores committed before release-add
        if (t < Tsz - 1) {
            if (tid == 0) {
                __hip_atomic_fetch_add(myc, 1u, __ATOMIC_RELAXED, __HIP_MEMORY_SCOPE_AGENT);
                unsigned target = 16u * (unsigned)(t + 1);
                long guard = 0;
                while (__hip_atomic_load(myc, __ATOMIC_RELAXED, __HIP_MEMORY_SCOPE_AGENT) < target) {
                    if (++guard > (1L << 22)) break;  // deadlock escape (never hit when resident)
                }
            }
            __syncthreads();
        }
    }
}

// ---- small-ws fallback path (round-2 design, correct but slower) ----------
__device__ __forceinline__ void matvec_acc(const float* __restrict__ WT, const float4* HV, int len,
                                           int col0, int col1, float a0[4], float a1[4]) {
    float wa0[4], wa1[4], wb0[4], wb1[4];
#pragma unroll
    for (int q = 0; q < 4; ++q) { wa0[q] = WT[q * Gsz + col0]; wa1[q] = WT[q * Gsz + col1]; }
    for (int k = 0; k < len; k += 8) {
#pragma unroll
        for (int q = 0; q < 4; ++q) {
            int kk = (k + 4 + q) & (len - 1);
            wb0[q] = WT[kk * Gsz + col0]; wb1[q] = WT[kk * Gsz + col1];
        }
#pragma unroll
        for (int q = 0; q < 4; ++q) {
            float4 hq = HV[k + q];
            a0[0] += wa0[q] * hq.x; a0[1] += wa0[q] * hq.y; a0[2] += wa0[q] * hq.z; a0[3] += wa0[q] * hq.w;
            a1[0] += wa1[q] * hq.x; a1[1] += wa1[q] * hq.y; a1[2] += wa1[q] * hq.z; a1[3] += wa1[q] * hq.w;
        }
#pragma unroll
        for (int q = 0; q < 4; ++q) {
            int kk = (k + 8 + q) & (len - 1);
            wa0[q] = WT[kk * Gsz + col0]; wa1[q] = WT[kk * Gsz + col1];
        }
#pragma unroll
        for (int q = 0; q < 4; ++q) {
            float4 hq = HV[k + 4 + q];
            a0[0] += wb0[q] * hq.x; a0[1] += wb0[q] * hq.y; a0[2] += wb0[q] * hq.z; a0[3] += wb0[q] * hq.w;
            a1[0] += wb1[q] * hq.x; a1[1] += wb1[q] * hq.y; a1[2] += wb1[q] * hq.z; a1[3] += wb1[q] * hq.w;
        }
    }
}

template <int XGF>
__global__ __launch_bounds__(512) void lstm_scan(const float* __restrict__ xgin,
                                                 const float* __restrict__ whhT,
                                                 const float* __restrict__ wihT,
                                                 const float* __restrict__ bih,
                                                 const float* __restrict__ bhh,
                                                 float* __restrict__ hs) {
    int j = threadIdx.x;
    int b0 = blockIdx.x * 4;
    int col0 = j, col1 = j + 512;
    __shared__ float4 h4[Hsz];
    __shared__ float4 x4[Esz];
    __shared__ float fo[2][4][Hsz];
    float c[4] = {0.f, 0.f, 0.f, 0.f};
    float bias0 = 0.f, bias1 = 0.f;
    if (XGF) { bias0 = bih[col0] + bhh[col0]; bias1 = bih[col1] + bhh[col1]; }
    if (j < Hsz) h4[j] = make_float4(0.f, 0.f, 0.f, 0.f);
    __syncthreads();
    for (int t = 0; t < Tsz; ++t) {
        float a0[4], a1[4];
        if (XGF) {
#pragma unroll
            for (int r = 0; r < 4; ++r) { a0[r] = bias0; a1[r] = bias1; }
            if (j < Esz) {
                float4 v;
                v.x = xgin[((size_t)(b0 + 0) * Tsz + t) * Esz + j];
                v.y = xgin[((size_t)(b0 + 1) * Tsz + t) * Esz + j];
                v.z = xgin[((size_t)(b0 + 2) * Tsz + t) * Esz + j];
                v.w = xgin[((size_t)(b0 + 3) * Tsz + t) * Esz + j];
                x4[j] = v;
            }
            __syncthreads();
            matvec_acc(wihT, x4, Esz, col0, col1, a0, a1);
        } else {
#pragma unroll
            for (int r = 0; r < 4; ++r) {
                a0[r] = xgin[((size_t)(b0 + r) * Tsz + t) * Gsz + col0];
                a1[r] = xgin[((size_t)(b0 + r) * Tsz + t) * Gsz + col1];
            }
        }
        matvec_acc(whhT, h4, Hsz, col0, col1, a0, a1);
        if (j < Hsz) {
#pragma unroll
            for (int r = 0; r < 4; ++r) { a0[r] = sigmoidf_(a0[r]); a1[r] = tanhf(a1[r]); }
        } else {
#pragma unroll
            for (int r = 0; r < 4; ++r) {
                fo[0][r][j - Hsz] = sigmoidf_(a0[r]);
                fo[1][r][j - Hsz] = sigmoidf_(a1[r]);
            }
        }
        __syncthreads();
        if (j < Hsz) {
            float hv[4];
#pragma unroll
            for (int r = 0; r < 4; ++r) {
                float f = fo[0][r][j], o = fo[1][r][j];
                c[r] = f * c[r] + a0[r] * a1[r];
                hv[r] = o * tanhf(c[r]);
                hs[(size_t)(b0 + r) * KFC + t * Hsz + j] = hv[r];
            }
            h4[j] = make_float4(hv[0], hv[1], hv[2], hv[3]);
        }
        __syncthreads();
    }
}

extern "C" void kernel_launch(void* const* d_in, const int* in_sizes, int n_in,
                              void* d_out, int out_size, void* d_ws, size_t ws_size,
                              hipStream_t stream) {
    const float* x    = (const float*)d_in[0];
    const float* w_ih = (const float*)d_in[1];
    const float* w_hh = (const float*)d_in[2];
    const float* b_ih = (const float*)d_in[3];
    const float* b_hh = (const float*)d_in[4];
    const float* w_fc = (const float*)d_in[5];
    const float* b_fc = (const float*)d_in[6];
    float* out = (float*)d_out;
    char* ws = (char*)d_ws;

    const size_t XG_BYTES = (size_t)Bsz * Tsz * Gsz * 4;    // 128 MB
    const size_t WT_BYTES = (size_t)Esz * Gsz * 4;          // 1 MB
    const size_t HS_BYTES = (size_t)Bsz * KFC * 4;          // 32 MB
    const size_t P_BYTES  = (size_t)KSPLIT * Bsz * Osz * 4; // 32 MB
    const size_t HB_BYTES = (size_t)NBI * 2 * 4096 * 4;     // 512 KB
    const size_t CNT_BYTES = (size_t)NBI * 32 * 4;          // 2 KB
    bool fast = ws_size >= XG_BYTES + WT_BYTES + HS_BYTES + P_BYTES + HB_BYTES + CNT_BYTES;

    const int KLEN = KFC / KSPLIT;  // 1024

    if (fast) {
        float* xg   = (float*)(ws);
        float* whhT = (float*)(ws + XG_BYTES);
        float* hsb  = (float*)(ws + XG_BYTES + WT_BYTES);
        float* part = (float*)(ws + XG_BYTES + WT_BYTES + HS_BYTES);
        float* hbuf = (float*)(ws + XG_BYTES + WT_BYTES + HS_BYTES + P_BYTES);
        unsigned int* cnt = (unsigned int*)(ws + XG_BYTES + WT_BYTES + HS_BYTES + P_BYTES + HB_BYTES);
        hipMemsetAsync(hbuf, 0, HB_BYTES + CNT_BYTES, stream);
        transpose_kn<<<(Esz * Gsz + 255) / 256, 256, 0, stream>>>(w_hh, whhT, Gsz, Esz);
        gemm128<1><<<dim3(Bsz * Tsz / 128, Gsz / 128, 1), 256, 0, stream>>>(
            x, Esz, w_ih, Esz, b_ih, b_hh, xg, Gsz, Esz);
        lstm_scan_coop2<<<dim3(NHJ, NBI), 1024, 0, stream>>>(xg, whhT, hsb, hbuf, cnt);
        gemm128<0><<<dim3(Bsz / 128, Osz / 128, KSPLIT), 256, 0, stream>>>(
            hsb, KFC, w_fc, KFC, nullptr, nullptr, part, Osz, KLEN);
        reduce_out<<<(Bsz * Osz + 255) / 256, 256, 0, stream>>>(part, b_fc, out);
    } else {
        float* whhT = (float*)(ws);
        float* wihT = (float*)(ws + WT_BYTES);
        float* hsb  = (float*)(ws + 2 * WT_BYTES);
        float* part = (float*)(ws + 2 * WT_BYTES + HS_BYTES);
        transpose_kn<<<(Esz * Gsz + 255) / 256, 256, 0, stream>>>(w_hh, whhT, Gsz, Esz);
        transpose_kn<<<(Esz * Gsz + 255) / 256, 256, 0, stream>>>(w_ih, wihT, Gsz, Esz);
        lstm_scan<1><<<Bsz / 4, 512, 0, stream>>>(x, whhT, wihT, b_ih, b_hh, hsb);
        gemm128<0><<<dim3(Bsz / 128, Osz / 128, KSPLIT), 256, 0, stream>>>(
            hsb, KFC, w_fc, KFC, nullptr, nullptr, part, Osz, KLEN);
        reduce_out<<<(Bsz * Osz + 255) / 256, 256, 0, stream>>>(part, b_fc, out);
    }
}